// Round 2
// baseline (398.689 us; speedup 1.0000x reference)
//
#include <hip/hip_runtime.h>
#include <math.h>

#define B_  128
#define N_  16
#define T_  200
#define H_  64
#define J1  80
#define J2  40
#define JC  40                 // layer-1 j-chunk size (2 chunks of 40)
#define NEGV -4294967295.0f   // -2^32 + 1

__device__ __forceinline__ float sigmoidf_(float x) {
    return 1.0f / (1.0f + __expf(-x));
}

// --- prep 0: combine W1 slices.  wac = W1a + W1c ; wbc = W1b - W1c -------
__global__ void prep_w(const float* __restrict__ W1,
                       float* __restrict__ wac, float* __restrict__ wbc) {
    int idx = blockIdx.x * 256 + threadIdx.x;          // idx = h*80 + j
    if (idx < H_ * J1) {
        wac[idx] = W1[idx]            + W1[128 * J1 + idx];
        wbc[idx] = W1[64 * J1 + idx]  - W1[128 * J1 + idx];
    }
}

// --- prep 1: QW[bn][j] = b1[j] + sum_h q[bn][h] * wac[h][j] --------------
__global__ void prep_qw(const float* __restrict__ q,
                        const float* __restrict__ wac,
                        const float* __restrict__ b1,
                        float* __restrict__ QW) {
    int idx = blockIdx.x * 256 + threadIdx.x;          // (bn, j/4)
    if (idx >= B_ * N_ * (J1 / 4)) return;
    int bn = idx / (J1 / 4);
    int j  = (idx % (J1 / 4)) * 4;
    float4 acc = *(const float4*)(b1 + j);
    const float* qp = q + bn * H_;
    for (int h = 0; h < H_; ++h) {
        float qh = qp[h];
        float4 w = *(const float4*)(wac + h * J1 + j);
        acc.x = fmaf(qh, w.x, acc.x);
        acc.y = fmaf(qh, w.y, acc.y);
        acc.z = fmaf(qh, w.z, acc.z);
        acc.w = fmaf(qh, w.w, acc.w);
    }
    *(float4*)(QW + bn * J1 + j) = acc;
}

// --- prep 2: KW[bt][j] = sum_h k[bt][h] * wbc[h][j] ----------------------
__global__ void prep_kw(const float* __restrict__ k,
                        const float* __restrict__ wbc,
                        float* __restrict__ KW) {
    int idx = blockIdx.x * 256 + threadIdx.x;          // (bt, j/4)
    if (idx >= B_ * T_ * (J1 / 4)) return;
    int bt = idx / (J1 / 4);
    int j  = (idx % (J1 / 4)) * 4;
    float4 acc = make_float4(0.f, 0.f, 0.f, 0.f);
    const float* kp = k + bt * H_;
    for (int h = 0; h < H_; ++h) {
        float kh = kp[h];
        float4 w = *(const float4*)(wbc + h * J1 + j);
        acc.x = fmaf(kh, w.x, acc.x);
        acc.y = fmaf(kh, w.y, acc.y);
        acc.z = fmaf(kh, w.z, acc.z);
        acc.w = fmaf(kh, w.w, acc.w);
    }
    *(float4*)(KW + bt * J1 + j) = acc;
}

// --- main: one block per (b,n); thread t owns key position t -------------
// Layer 1 is computed in two j-chunks of 40 so that z1c[40] + z2[40] fit in
// VGPRs (no compiler loop-interchange, which round-1 showed costs 3x in
// per-j kT re-reads). W rows are block-uniform -> s_load (scalar pipe).
template <bool USE_WS>
__global__ __launch_bounds__(256, 3) void attn_main(
        const float* __restrict__ queries, const float* __restrict__ keys,
        const int*   __restrict__ keys_length,
        const float* __restrict__ W1, const float* __restrict__ b1,
        const float* __restrict__ W2, const float* __restrict__ b2,
        const float* __restrict__ W3, const float* __restrict__ b3,
        const float* __restrict__ QW, const float* __restrict__ KW,
        float* __restrict__ out) {
    const int tid = threadIdx.x;
    // XCD-aware swizzle: 2048 blocks, 8 XCDs, round-robin dispatch.
    // XCD c gets bn in [256c, 256c+256) -> 16 consecutive b share one L2.
    const int bn = (blockIdx.x & 7) * 256 + (blockIdx.x >> 3);
    const int b  = bn >> 4;

    __shared__ float kT[H_][T_ + 1];   // 64 x 201, pad kills staging-write conflicts
    __shared__ float wsm[T_];
    __shared__ float part[256];
    __shared__ float red[8];
    __shared__ float QWq[J1];

    // stage keys transposed: kT[h][t] (coalesced global read, stride-201 LDS write)
    for (int idx = tid; idx < T_ * H_; idx += 256) {
        int t = idx >> 6, h = idx & 63;
        kT[h][t] = keys[(b * T_ + t) * H_ + h];
    }
    if (!USE_WS) {
        if (tid < J1) {
            float acc = b1[tid];
            const float* qp = queries + bn * H_;
            for (int h = 0; h < H_; ++h)
                acc = fmaf(qp[h], W1[h * J1 + tid] + W1[(128 + h) * J1 + tid], acc);
            QWq[tid] = acc;
        }
    }
    __syncthreads();

    const int   tt = (tid < T_) ? tid : 0;   // clamp: inactive lanes read valid data
    const float* qp  = queries + bn * H_;                       // uniform -> s_load
    const float* KWp = USE_WS ? KW + (size_t)(b * T_ + tt) * J1 : nullptr;
    const float* QWp = USE_WS ? QW + bn * J1 : QWq;             // uniform

    float z2[J2];
    #pragma unroll
    for (int m = 0; m < J2; ++m) z2[m] = b2[m];

    #pragma unroll 1
    for (int c = 0; c < J1 / JC; ++c) {
        const int j0 = c * JC;
        float z1c[JC];
        if (USE_WS) {
            #pragma unroll
            for (int j = 0; j < JC; j += 4) {
                float4 kw = *(const float4*)(KWp + j0 + j);
                z1c[j]     = QWp[j0 + j]     + kw.x;
                z1c[j + 1] = QWp[j0 + j + 1] + kw.y;
                z1c[j + 2] = QWp[j0 + j + 2] + kw.z;
                z1c[j + 3] = QWp[j0 + j + 3] + kw.w;
            }
        } else {
            #pragma unroll
            for (int j = 0; j < JC; ++j) z1c[j] = QWq[j0 + j];
        }

        // z1c[j] += (q_h*k_h) * W1d[h][j0+j]
        #pragma unroll 4
        for (int h = 0; h < H_; ++h) {
            float kh = kT[h][tt];
            float qk = qp[h] * kh;
            const float* Wd = W1 + (192 + h) * J1 + j0;          // uniform -> s_load
            if (USE_WS) {
                #pragma unroll
                for (int j = 0; j < JC; ++j)
                    z1c[j] = fmaf(qk, Wd[j], z1c[j]);
            } else {
                const float* Wb = W1 + (64 + h) * J1 + j0;
                const float* Wc = W1 + (128 + h) * J1 + j0;
                #pragma unroll
                for (int j = 0; j < JC; ++j)
                    z1c[j] = fmaf(qk, Wd[j], fmaf(kh, Wb[j] - Wc[j], z1c[j]));
            }
        }

        // layer 2: consume this chunk immediately (z1c dies here)
        #pragma unroll 4
        for (int j = 0; j < JC; ++j) {
            float x = sigmoidf_(z1c[j]);
            const float* w2 = W2 + (j0 + j) * J2;                // uniform -> s_load
            #pragma unroll
            for (int m = 0; m < J2; ++m) z2[m] = fmaf(x, w2[m], z2[m]);
        }
    }

    // layer 3
    float z3 = b3[0];
    #pragma unroll
    for (int m = 0; m < J2; ++m) z3 = fmaf(sigmoidf_(z2[m]), W3[m], z3);

    // mask + scale (reference order: mask to NEG, then /sqrt(H))
    const int L = keys_length[b];
    float s = (tid < T_) ? ((tid < L) ? z3 : NEGV) * 0.125f : -3.0e38f;

    // softmax across the block (200 valid lanes)
    float mx = s;
    #pragma unroll
    for (int off = 32; off > 0; off >>= 1) mx = fmaxf(mx, __shfl_xor(mx, off));
    if ((tid & 63) == 0) red[tid >> 6] = mx;
    __syncthreads();
    mx = fmaxf(fmaxf(red[0], red[1]), fmaxf(red[2], red[3]));

    float e = (tid < T_) ? __expf(s - mx) : 0.0f;    // masked t: exp(-5.4e8) = 0
    float sm = e;
    #pragma unroll
    for (int off = 32; off > 0; off >>= 1) sm += __shfl_xor(sm, off);
    __syncthreads();                                 // red[0..3] fully read
    if ((tid & 63) == 0) red[4 + (tid >> 6)] = sm;
    __syncthreads();
    sm = red[4] + red[5] + red[6] + red[7];

    if (tid < T_) wsm[tid] = e / sm;
    __syncthreads();

    // out[h] = sum_t w[t] * kT[h][t]; 4 waves each take 50 t's
    {
        int h = tid & 63, p = tid >> 6;
        float acc = 0.f;
        int t0 = p * 50;
        for (int t = t0; t < t0 + 50; ++t)
            acc = fmaf(wsm[t], kT[h][t], acc);
        part[tid] = acc;
    }
    __syncthreads();
    if (tid < 64) {
        float o = part[tid] + part[64 + tid] + part[128 + tid] + part[192 + tid];
        out[bn * H_ + tid] = o;
    }
}

extern "C" void kernel_launch(void* const* d_in, const int* in_sizes, int n_in,
                              void* d_out, int out_size, void* d_ws, size_t ws_size,
                              hipStream_t stream) {
    const float* queries = (const float*)d_in[0];
    const float* keys    = (const float*)d_in[1];
    const int*   klen    = (const int*)  d_in[2];
    const float* W1 = (const float*)d_in[3];
    const float* b1 = (const float*)d_in[4];
    const float* W2 = (const float*)d_in[5];
    const float* b2 = (const float*)d_in[6];
    const float* W3 = (const float*)d_in[7];
    const float* b3 = (const float*)d_in[8];
    float* out = (float*)d_out;

    const size_t need = (size_t)(2 * H_ * J1 + B_ * N_ * J1 + B_ * T_ * J1) * sizeof(float);

    if (ws_size >= need) {
        float* wac = (float*)d_ws;
        float* wbc = wac + H_ * J1;
        float* QW  = wbc + H_ * J1;
        float* KW  = QW + B_ * N_ * J1;
        prep_w <<<dim3((H_ * J1 + 255) / 256),           dim3(256), 0, stream>>>(W1, wac, wbc);
        prep_qw<<<dim3((B_ * N_ * (J1/4) + 255) / 256),  dim3(256), 0, stream>>>(queries, wac, b1, QW);
        prep_kw<<<dim3((B_ * T_ * (J1/4) + 255) / 256),  dim3(256), 0, stream>>>(keys, wbc, KW);
        attn_main<true><<<dim3(B_ * N_), dim3(256), 0, stream>>>(
            queries, keys, klen, W1, b1, W2, b2, W3, b3, QW, KW, out);
    } else {
        attn_main<false><<<dim3(B_ * N_), dim3(256), 0, stream>>>(
            queries, keys, klen, W1, b1, W2, b2, W3, b3,
            (const float*)nullptr, (const float*)nullptr, out);
    }
}

// Round 3
// 245.303 us; speedup vs baseline: 1.6253x; 1.6253x over previous
//
#include <hip/hip_runtime.h>
#include <math.h>

#define B_  128
#define N_  16
#define T_  200
#define H_  64
#define J1  80
#define J2  40
#define JC  20                 // layer-1 j-chunk size (4 chunks of 20)
#define NEGV -4294967295.0f   // -2^32 + 1

__device__ __forceinline__ float sigmoidf_(float x) {
    return 1.0f / (1.0f + __expf(-x));
}

// --- prep 0: combine W1 slices.  wac = W1a + W1c ; wbc = W1b - W1c -------
__global__ void prep_w(const float* __restrict__ W1,
                       float* __restrict__ wac, float* __restrict__ wbc) {
    int idx = blockIdx.x * 256 + threadIdx.x;          // idx = h*80 + j
    if (idx < H_ * J1) {
        wac[idx] = W1[idx]            + W1[128 * J1 + idx];
        wbc[idx] = W1[64 * J1 + idx]  - W1[128 * J1 + idx];
    }
}

// --- prep 1: QW[bn][j] = b1[j] + sum_h q[bn][h] * wac[h][j] --------------
__global__ void prep_qw(const float* __restrict__ q,
                        const float* __restrict__ wac,
                        const float* __restrict__ b1,
                        float* __restrict__ QW) {
    int idx = blockIdx.x * 256 + threadIdx.x;          // (bn, j/4)
    if (idx >= B_ * N_ * (J1 / 4)) return;
    int bn = idx / (J1 / 4);
    int j  = (idx % (J1 / 4)) * 4;
    float4 acc = *(const float4*)(b1 + j);
    const float* qp = q + bn * H_;
    for (int h = 0; h < H_; ++h) {
        float qh = qp[h];
        float4 w = *(const float4*)(wac + h * J1 + j);
        acc.x = fmaf(qh, w.x, acc.x);
        acc.y = fmaf(qh, w.y, acc.y);
        acc.z = fmaf(qh, w.z, acc.z);
        acc.w = fmaf(qh, w.w, acc.w);
    }
    *(float4*)(QW + bn * J1 + j) = acc;
}

// --- prep 2: KW[bt][j] = sum_h k[bt][h] * wbc[h][j] ----------------------
__global__ void prep_kw(const float* __restrict__ k,
                        const float* __restrict__ wbc,
                        float* __restrict__ KW) {
    int idx = blockIdx.x * 256 + threadIdx.x;          // (bt, j/4)
    if (idx >= B_ * T_ * (J1 / 4)) return;
    int bt = idx / (J1 / 4);
    int j  = (idx % (J1 / 4)) * 4;
    float4 acc = make_float4(0.f, 0.f, 0.f, 0.f);
    const float* kp = k + bt * H_;
    for (int h = 0; h < H_; ++h) {
        float kh = kp[h];
        float4 w = *(const float4*)(wbc + h * J1 + j);
        acc.x = fmaf(kh, w.x, acc.x);
        acc.y = fmaf(kh, w.y, acc.y);
        acc.z = fmaf(kh, w.z, acc.z);
        acc.w = fmaf(kh, w.w, acc.w);
    }
    *(float4*)(KW + bt * J1 + j) = acc;
}

// --- main: one block per (b,n); thread t owns key position t -------------
// qk[64] is materialized in VGPRs ONCE (kills round-1's per-j kT re-read
// restructure). ALL per-thread arrays use compile-time indices only
// (rule #20 — round-2's partial unroll demoted z1c to scratch: 257 MB
// WRITE_SIZE). j chunked 4x20 so qk[64]+z1c[20]+z2[40] ~ 150 VGPR < 170.
template <bool USE_WS>
__global__ __launch_bounds__(256, 3) void attn_main(
        const float* __restrict__ queries, const float* __restrict__ keys,
        const int*   __restrict__ keys_length,
        const float* __restrict__ W1, const float* __restrict__ b1,
        const float* __restrict__ W2, const float* __restrict__ b2,
        const float* __restrict__ W3, const float* __restrict__ b3,
        const float* __restrict__ QW, const float* __restrict__ KW,
        float* __restrict__ out) {
    const int tid = threadIdx.x;
    // XCD-aware swizzle: 2048 blocks, 8 XCDs, round-robin dispatch.
    const int bn = (blockIdx.x & 7) * 256 + (blockIdx.x >> 3);
    const int b  = bn >> 4;

    __shared__ float kT[H_][T_ + 1];   // 64 x 201 (pad: staging writes hit all banks)
    __shared__ float wsm[T_];
    __shared__ float part[256];
    __shared__ float red[8];
    __shared__ float QWq[J1];

    // stage keys transposed: kT[h][t]
    for (int idx = tid; idx < T_ * H_; idx += 256) {
        int t = idx >> 6, h = idx & 63;
        kT[h][t] = keys[(b * T_ + t) * H_ + h];
    }
    if (!USE_WS) {
        if (tid < J1) {
            float acc = b1[tid];
            const float* qp = queries + bn * H_;
            for (int h = 0; h < H_; ++h)
                acc = fmaf(qp[h], W1[h * J1 + tid] + W1[(128 + h) * J1 + tid], acc);
            QWq[tid] = acc;
        }
    }
    __syncthreads();

    const int   tt = (tid < T_) ? tid : 0;   // clamp: inactive lanes read valid data
    const float* qp  = queries + bn * H_;                       // uniform -> s_load
    const float* KWp = USE_WS ? KW + (size_t)(b * T_ + tt) * J1 : nullptr;

    // qk[h] in VGPRs, computed once: 64 ds_reads total per thread
    float qk[H_];
    #pragma unroll
    for (int h = 0; h < H_; ++h) qk[h] = qp[h] * kT[h][tt];

    float z2[J2];
    #pragma unroll
    for (int m = 0; m < J2; ++m) z2[m] = b2[m];

    #pragma unroll 1
    for (int c = 0; c < J1 / JC; ++c) {
        const int j0 = c * JC;            // runtime, feeds POINTERS only
        float z1c[JC];
        if (USE_WS) {
            const float* QWp = QW + bn * J1 + j0;               // uniform
            #pragma unroll
            for (int j = 0; j < JC; j += 4) {
                float4 kw = *(const float4*)(KWp + j0 + j);
                z1c[j]     = QWp[j]     + kw.x;
                z1c[j + 1] = QWp[j + 1] + kw.y;
                z1c[j + 2] = QWp[j + 2] + kw.z;
                z1c[j + 3] = QWp[j + 3] + kw.w;
            }
        } else {
            #pragma unroll
            for (int j = 0; j < JC; ++j) z1c[j] = QWq[j0 + j];
        }

        // z1c[j] += qk[h] * W1d[h][j0+j]   (all indices compile-time)
        #pragma unroll
        for (int h = 0; h < H_; ++h) {
            const float* Wd = W1 + (192 + h) * J1 + j0;          // uniform -> s_load
            if (USE_WS) {
                #pragma unroll
                for (int j = 0; j < JC; ++j)
                    z1c[j] = fmaf(qk[h], Wd[j], z1c[j]);
            } else {
                float kh = kT[h][tt];
                const float* Wb = W1 + (64 + h) * J1 + j0;
                const float* Wc = W1 + (128 + h) * J1 + j0;
                #pragma unroll
                for (int j = 0; j < JC; ++j)
                    z1c[j] = fmaf(qk[h], Wd[j], fmaf(kh, Wb[j] - Wc[j], z1c[j]));
            }
        }

        // layer 2: consume this chunk immediately (z1c dies here)
        #pragma unroll
        for (int j = 0; j < JC; ++j) {
            float x = sigmoidf_(z1c[j]);
            const float* w2 = W2 + (j0 + j) * J2;                // uniform -> s_load
            #pragma unroll
            for (int m = 0; m < J2; ++m) z2[m] = fmaf(x, w2[m], z2[m]);
        }
    }

    // layer 3
    float z3 = b3[0];
    #pragma unroll
    for (int m = 0; m < J2; ++m) z3 = fmaf(sigmoidf_(z2[m]), W3[m], z3);

    // mask + scale (reference order: mask to NEG, then /sqrt(H))
    const int L = keys_length[b];
    float s = (tid < T_) ? ((tid < L) ? z3 : NEGV) * 0.125f : -3.0e38f;

    // softmax across the block (200 valid lanes)
    float mx = s;
    #pragma unroll
    for (int off = 32; off > 0; off >>= 1) mx = fmaxf(mx, __shfl_xor(mx, off));
    if ((tid & 63) == 0) red[tid >> 6] = mx;
    __syncthreads();
    mx = fmaxf(fmaxf(red[0], red[1]), fmaxf(red[2], red[3]));

    float e = (tid < T_) ? __expf(s - mx) : 0.0f;    // masked t: exp(-5.4e8) = 0
    float sm = e;
    #pragma unroll
    for (int off = 32; off > 0; off >>= 1) sm += __shfl_xor(sm, off);
    __syncthreads();
    if ((tid & 63) == 0) red[4 + (tid >> 6)] = sm;
    __syncthreads();
    sm = red[4] + red[5] + red[6] + red[7];

    if (tid < T_) wsm[tid] = e / sm;
    __syncthreads();

    // out[h] = sum_t w[t] * kT[h][t]; 4 waves each take 50 t's
    {
        int h = tid & 63, p = tid >> 6;
        float acc = 0.f;
        int t0 = p * 50;
        for (int t = t0; t < t0 + 50; ++t)
            acc = fmaf(wsm[t], kT[h][t], acc);
        part[tid] = acc;
    }
    __syncthreads();
    if (tid < 64) {
        float o = part[tid] + part[64 + tid] + part[128 + tid] + part[192 + tid];
        out[bn * H_ + tid] = o;
    }
}

extern "C" void kernel_launch(void* const* d_in, const int* in_sizes, int n_in,
                              void* d_out, int out_size, void* d_ws, size_t ws_size,
                              hipStream_t stream) {
    const float* queries = (const float*)d_in[0];
    const float* keys    = (const float*)d_in[1];
    const int*   klen    = (const int*)  d_in[2];
    const float* W1 = (const float*)d_in[3];
    const float* b1 = (const float*)d_in[4];
    const float* W2 = (const float*)d_in[5];
    const float* b2 = (const float*)d_in[6];
    const float* W3 = (const float*)d_in[7];
    const float* b3 = (const float*)d_in[8];
    float* out = (float*)d_out;

    const size_t need = (size_t)(2 * H_ * J1 + B_ * N_ * J1 + B_ * T_ * J1) * sizeof(float);

    if (ws_size >= need) {
        float* wac = (float*)d_ws;
        float* wbc = wac + H_ * J1;
        float* QW  = wbc + H_ * J1;
        float* KW  = QW + B_ * N_ * J1;
        prep_w <<<dim3((H_ * J1 + 255) / 256),           dim3(256), 0, stream>>>(W1, wac, wbc);
        prep_qw<<<dim3((B_ * N_ * (J1/4) + 255) / 256),  dim3(256), 0, stream>>>(queries, wac, b1, QW);
        prep_kw<<<dim3((B_ * T_ * (J1/4) + 255) / 256),  dim3(256), 0, stream>>>(keys, wbc, KW);
        attn_main<true><<<dim3(B_ * N_), dim3(256), 0, stream>>>(
            queries, keys, klen, W1, b1, W2, b2, W3, b3, QW, KW, out);
    } else {
        attn_main<false><<<dim3(B_ * N_), dim3(256), 0, stream>>>(
            queries, keys, klen, W1, b1, W2, b2, W3, b3,
            (const float*)nullptr, (const float*)nullptr, out);
    }
}

// Round 4
// 126.772 us; speedup vs baseline: 3.1449x; 1.9350x over previous
//
#include <hip/hip_runtime.h>
#include <hip/hip_bf16.h>
#include <math.h>

#define B_  128
#define N_  16
#define T_  200
#define H_  64
#define J1  80
#define J2  40
#define NEGV -4294967295.0f   // -2^32 + 1

typedef __attribute__((ext_vector_type(8))) short bf16x8;
typedef __attribute__((ext_vector_type(4))) float f32x4;

__device__ __forceinline__ float sigmoidf_(float x) {
    return 1.0f / (1.0f + __expf(-x));
}
__device__ __forceinline__ short f2b(float x) {
    __hip_bfloat16 h = __float2bfloat16(x);
    return *reinterpret_cast<short*>(&h);
}
__device__ __forceinline__ unsigned pack2(float a, float b) {
    return (unsigned)(unsigned short)f2b(a) | ((unsigned)(unsigned short)f2b(b) << 16);
}

// --- prep 0: wac = W1a + W1c ; wbc = W1b - W1c ---------------------------
__global__ void prep_w(const float* __restrict__ W1,
                       float* __restrict__ wac, float* __restrict__ wbc) {
    int idx = blockIdx.x * 256 + threadIdx.x;          // idx = h*80 + j
    if (idx < H_ * J1) {
        wac[idx] = W1[idx]            + W1[128 * J1 + idx];
        wbc[idx] = W1[64 * J1 + idx]  - W1[128 * J1 + idx];
    }
}

// --- prep 1: QW[bn][j] = b1[j] + sum_h q[bn][h] * wac[h][j] --------------
__global__ void prep_qw(const float* __restrict__ q,
                        const float* __restrict__ wac,
                        const float* __restrict__ b1,
                        float* __restrict__ QW) {
    int idx = blockIdx.x * 256 + threadIdx.x;
    if (idx >= B_ * N_ * (J1 / 4)) return;
    int bn = idx / (J1 / 4);
    int j  = (idx % (J1 / 4)) * 4;
    float4 acc = *(const float4*)(b1 + j);
    const float* qp = q + bn * H_;
    for (int h = 0; h < H_; ++h) {
        float qh = qp[h];
        float4 w = *(const float4*)(wac + h * J1 + j);
        acc.x = fmaf(qh, w.x, acc.x);
        acc.y = fmaf(qh, w.y, acc.y);
        acc.z = fmaf(qh, w.z, acc.z);
        acc.w = fmaf(qh, w.w, acc.w);
    }
    *(float4*)(QW + bn * J1 + j) = acc;
}

// --- prep 2: KW[bt][j] = sum_h k[bt][h] * wbc[h][j] ----------------------
__global__ void prep_kw(const float* __restrict__ k,
                        const float* __restrict__ wbc,
                        float* __restrict__ KW) {
    int idx = blockIdx.x * 256 + threadIdx.x;
    if (idx >= B_ * T_ * (J1 / 4)) return;
    int bt = idx / (J1 / 4);
    int j  = (idx % (J1 / 4)) * 4;
    float4 acc = make_float4(0.f, 0.f, 0.f, 0.f);
    const float* kp = k + bt * H_;
    for (int h = 0; h < H_; ++h) {
        float kh = kp[h];
        float4 w = *(const float4*)(wbc + h * J1 + j);
        acc.x = fmaf(kh, w.x, acc.x);
        acc.y = fmaf(kh, w.y, acc.y);
        acc.z = fmaf(kh, w.z, acc.z);
        acc.w = fmaf(kh, w.w, acc.w);
    }
    *(float4*)(KW + bt * J1 + j) = acc;
}

// --- prep 3: W1d -> frag-ordered bf16 B-fragments ------------------------
// frag f = nt*2 + ks (nt<5, ks<2); lane l holds B[k][j]: k = ks*32+8*(l>>4)+r,
// j = nt*16 + (l&15). Stored as uints: idx = f*256 + l*4 + rp (r = 2rp, 2rp+1).
__global__ void prep_w1f(const float* __restrict__ W1, unsigned* __restrict__ W1F) {
    int idx = blockIdx.x * 256 + threadIdx.x;
    if (idx >= 10 * 64 * 4) return;
    int rp = idx & 3;
    int l  = (idx >> 2) & 63;
    int f  = idx >> 8;
    int nt = f >> 1, ks = f & 1;
    int j  = nt * 16 + (l & 15);
    int k0 = ks * 32 + 8 * (l >> 4) + 2 * rp;
    float a = W1[(192 + k0) * J1 + j];
    float b = W1[(192 + k0 + 1) * J1 + j];
    W1F[idx] = pack2(a, b);
}

// --- prep 4: W2 -> frag-ordered bf16 (padded k to 96, cols to 48) --------
// frag f = nt*3 + ks (nt<3, ks<3): k = ks*32+8*(l>>4)+r, m = nt*16+(l&15).
__global__ void prep_w2f(const float* __restrict__ W2, unsigned* __restrict__ W2F) {
    int idx = blockIdx.x * 256 + threadIdx.x;
    if (idx >= 9 * 64 * 4) return;
    int rp = idx & 3;
    int l  = (idx >> 2) & 63;
    int f  = idx >> 8;
    int m  = (f / 3) * 16 + (l & 15);
    int k0 = (f % 3) * 32 + 8 * (l >> 4) + 2 * rp;
    float a = (k0     < J1 && m < J2) ? W2[k0 * J2 + m]       : 0.0f;
    float b = (k0 + 1 < J1 && m < J2) ? W2[(k0 + 1) * J2 + m] : 0.0f;
    W2F[idx] = pack2(a, b);
}

// --- main (MFMA): one block per (b,n), 4 waves over 13 M-tiles of 16 -----
__global__ __launch_bounds__(256) void attn_mfma(
        const float* __restrict__ queries, const float* __restrict__ keys,
        const int*   __restrict__ keys_length,
        const float* __restrict__ b2, const float* __restrict__ W3,
        const float* __restrict__ b3,
        const float* __restrict__ QW, const float* __restrict__ KW,
        const bf16x8* __restrict__ W1F, const bf16x8* __restrict__ W2F,
        float* __restrict__ out) {
    const int tid  = threadIdx.x;
    const int lane = tid & 63, wv = tid >> 6;
    const int bn   = (blockIdx.x & 7) * 256 + (blockIdx.x >> 3);  // XCD swizzle
    const int b    = bn >> 4;
    const int cl   = lane & 15, rg = lane >> 4;

    __shared__ __align__(16) short X1[4][16][104];  // per-wave; stride 104 -> banks spread
    __shared__ float z3s[13 * 16];
    __shared__ float wsm[T_];
    __shared__ float part[256];
    __shared__ float red[8];

    // zero X1 k-pad (cols 80..103) once; pad rows of W2F are zero so pad A*0=0
    for (int i = lane; i < 16 * 24; i += 64)
        X1[wv][i / 24][80 + (i % 24)] = 0;

    // B fragments resident in VGPRs (shared across all M-tiles of this wave)
    bf16x8 w1f[10];
    #pragma unroll
    for (int f = 0; f < 10; ++f) w1f[f] = W1F[f * 64 + lane];
    bf16x8 w2f[9];
    #pragma unroll
    for (int f = 0; f < 9; ++f) w2f[f] = W2F[f * 64 + lane];

    // q fragments: h = ks*32 + 8*rg + r
    const float* qp = queries + bn * H_;
    float4 q0a = *(const float4*)(qp + 8 * rg);
    float4 q0b = *(const float4*)(qp + 8 * rg + 4);
    float4 q1a = *(const float4*)(qp + 32 + 8 * rg);
    float4 q1b = *(const float4*)(qp + 32 + 8 * rg + 4);

    float qwv[5];
    #pragma unroll
    for (int nt = 0; nt < 5; ++nt) qwv[nt] = QW[bn * J1 + cl + 16 * nt];
    float b2v[3], w3v[3];
    #pragma unroll
    for (int nt = 0; nt < 3; ++nt) {
        int m  = cl + 16 * nt;
        int mc = m < J2 ? m : J2 - 1;
        b2v[nt] = b2[mc];
        w3v[nt] = (m < J2) ? W3[mc] : 0.0f;
    }
    const float b3v = b3[0];
    const float* kb  = keys + (size_t)b * T_ * H_;
    const float* kwb = KW   + (size_t)b * T_ * J1;

    for (int mt = wv; mt < 13; mt += 4) {
        const int t0 = mt * 16;
        // ---- A fragments: QK[t][h] = q[h]*k[t][h], row t = t0 + cl ----
        int ta = t0 + cl; if (ta > T_ - 1) ta = T_ - 1;   // clamp tail rows
        const float* kr = kb + (size_t)ta * H_ + 8 * rg;
        float4 k0a = *(const float4*)(kr);
        float4 k0b = *(const float4*)(kr + 4);
        float4 k1a = *(const float4*)(kr + 32);
        float4 k1b = *(const float4*)(kr + 36);
        bf16x8 af0, af1;
        af0[0] = f2b(q0a.x * k0a.x); af0[1] = f2b(q0a.y * k0a.y);
        af0[2] = f2b(q0a.z * k0a.z); af0[3] = f2b(q0a.w * k0a.w);
        af0[4] = f2b(q0b.x * k0b.x); af0[5] = f2b(q0b.y * k0b.y);
        af0[6] = f2b(q0b.z * k0b.z); af0[7] = f2b(q0b.w * k0b.w);
        af1[0] = f2b(q1a.x * k1a.x); af1[1] = f2b(q1a.y * k1a.y);
        af1[2] = f2b(q1a.z * k1a.z); af1[3] = f2b(q1a.w * k1a.w);
        af1[4] = f2b(q1b.x * k1b.x); af1[5] = f2b(q1b.y * k1b.y);
        af1[6] = f2b(q1b.z * k1b.z); af1[7] = f2b(q1b.w * k1b.w);

        // ---- layer 1: Z1 = QK @ W1d ----
        f32x4 acc[5];
        #pragma unroll
        for (int nt = 0; nt < 5; ++nt) { acc[nt][0]=0.f; acc[nt][1]=0.f; acc[nt][2]=0.f; acc[nt][3]=0.f; }
        #pragma unroll
        for (int nt = 0; nt < 5; ++nt) {
            acc[nt] = __builtin_amdgcn_mfma_f32_16x16x32_bf16(af0, w1f[nt * 2 + 0], acc[nt], 0, 0, 0);
            acc[nt] = __builtin_amdgcn_mfma_f32_16x16x32_bf16(af1, w1f[nt * 2 + 1], acc[nt], 0, 0, 0);
        }

        // ---- + QW + KW, sigmoid, store X1 (C layout: row=(rg*4+i), col=cl+16nt)
        #pragma unroll
        for (int nt = 0; nt < 5; ++nt) {
            #pragma unroll
            for (int i = 0; i < 4; ++i) {
                int t = t0 + rg * 4 + i; int tc = t < T_ ? t : T_ - 1;
                float z = acc[nt][i] + qwv[nt] + kwb[(size_t)tc * J1 + cl + 16 * nt];
                X1[wv][rg * 4 + i][cl + 16 * nt] = f2b(sigmoidf_(z));
            }
        }

        // ---- layer 2: Z2 = X1 @ W2 (A from per-wave LDS; same-wave ordering)
        f32x4 acc2[3];
        #pragma unroll
        for (int nt = 0; nt < 3; ++nt) { acc2[nt][0]=0.f; acc2[nt][1]=0.f; acc2[nt][2]=0.f; acc2[nt][3]=0.f; }
        #pragma unroll
        for (int ks = 0; ks < 3; ++ks) {
            bf16x8 a2 = *(const bf16x8*)&X1[wv][cl][8 * rg + 32 * ks];
            acc2[0] = __builtin_amdgcn_mfma_f32_16x16x32_bf16(a2, w2f[0 + ks], acc2[0], 0, 0, 0);
            acc2[1] = __builtin_amdgcn_mfma_f32_16x16x32_bf16(a2, w2f[3 + ks], acc2[1], 0, 0, 0);
            acc2[2] = __builtin_amdgcn_mfma_f32_16x16x32_bf16(a2, w2f[6 + ks], acc2[2], 0, 0, 0);
        }

        // ---- layer 3: z3[t] = sum_m sigmoid(z2[t][m]) * W3[m] ----
        float p0 = 0.f, p1 = 0.f, p2 = 0.f, p3 = 0.f;
        #pragma unroll
        for (int nt = 0; nt < 3; ++nt) {
            p0 = fmaf(sigmoidf_(acc2[nt][0] + b2v[nt]), w3v[nt], p0);
            p1 = fmaf(sigmoidf_(acc2[nt][1] + b2v[nt]), w3v[nt], p1);
            p2 = fmaf(sigmoidf_(acc2[nt][2] + b2v[nt]), w3v[nt], p2);
            p3 = fmaf(sigmoidf_(acc2[nt][3] + b2v[nt]), w3v[nt], p3);
        }
        #pragma unroll
        for (int off = 1; off < 16; off <<= 1) {
            p0 += __shfl_xor(p0, off);
            p1 += __shfl_xor(p1, off);
            p2 += __shfl_xor(p2, off);
            p3 += __shfl_xor(p3, off);
        }
        if (cl == 0) {
            z3s[t0 + rg * 4 + 0] = p0 + b3v;
            z3s[t0 + rg * 4 + 1] = p1 + b3v;
            z3s[t0 + rg * 4 + 2] = p2 + b3v;
            z3s[t0 + rg * 4 + 3] = p3 + b3v;
        }
    }
    __syncthreads();

    // ---- mask + scale + softmax (thread tid owns t=tid) ----
    const int L = keys_length[b];
    float s = (tid < T_) ? ((tid < L) ? z3s[tid] : NEGV) * 0.125f : -3.0e38f;

    float mx = s;
    #pragma unroll
    for (int off = 32; off > 0; off >>= 1) mx = fmaxf(mx, __shfl_xor(mx, off));
    if ((tid & 63) == 0) red[tid >> 6] = mx;
    __syncthreads();
    mx = fmaxf(fmaxf(red[0], red[1]), fmaxf(red[2], red[3]));

    float e = (tid < T_) ? __expf(s - mx) : 0.0f;
    float sm = e;
    #pragma unroll
    for (int off = 32; off > 0; off >>= 1) sm += __shfl_xor(sm, off);
    __syncthreads();
    if ((tid & 63) == 0) red[4 + (tid >> 6)] = sm;
    __syncthreads();
    sm = red[4] + red[5] + red[6] + red[7];

    if (tid < T_) wsm[tid] = e / sm;
    __syncthreads();

    // ---- out[h] = sum_t w[t] * keys[b][t][h] (keys L2-hot, coalesced) ----
    {
        int h = tid & 63, p = tid >> 6;
        float acc = 0.f;
        int tb = p * 50;
        #pragma unroll 5
        for (int t = tb; t < tb + 50; ++t)
            acc = fmaf(wsm[t], kb[(size_t)t * H_ + h], acc);
        part[tid] = acc;
    }
    __syncthreads();
    if (tid < 64) {
        out[bn * H_ + tid] = part[tid] + part[64 + tid] + part[128 + tid] + part[192 + tid];
    }
}

// --- fallback (no workspace): round-3 verified pure-VALU kernel ----------
__global__ __launch_bounds__(256, 3) void attn_nows(
        const float* __restrict__ queries, const float* __restrict__ keys,
        const int*   __restrict__ keys_length,
        const float* __restrict__ W1, const float* __restrict__ b1,
        const float* __restrict__ W2, const float* __restrict__ b2,
        const float* __restrict__ W3, const float* __restrict__ b3,
        float* __restrict__ out) {
    const int tid = threadIdx.x;
    const int bn = (blockIdx.x & 7) * 256 + (blockIdx.x >> 3);
    const int b  = bn >> 4;

    __shared__ float kT[H_][T_ + 1];
    __shared__ float wsm[T_];
    __shared__ float part[256];
    __shared__ float red[8];
    __shared__ float QWq[J1];

    for (int idx = tid; idx < T_ * H_; idx += 256) {
        int t = idx >> 6, h = idx & 63;
        kT[h][t] = keys[(b * T_ + t) * H_ + h];
    }
    if (tid < J1) {
        float acc = b1[tid];
        const float* qp = queries + bn * H_;
        for (int h = 0; h < H_; ++h)
            acc = fmaf(qp[h], W1[h * J1 + tid] + W1[(128 + h) * J1 + tid], acc);
        QWq[tid] = acc;
    }
    __syncthreads();

    const int tt = (tid < T_) ? tid : 0;
    const float* qp = queries + bn * H_;

    float qk[H_];
    #pragma unroll
    for (int h = 0; h < H_; ++h) qk[h] = qp[h] * kT[h][tt];

    float z2[J2];
    #pragma unroll
    for (int m = 0; m < J2; ++m) z2[m] = b2[m];

    #pragma unroll 1
    for (int c = 0; c < 4; ++c) {
        const int j0 = c * 20;
        float z1c[20];
        #pragma unroll
        for (int j = 0; j < 20; ++j) z1c[j] = QWq[j0 + j];
        #pragma unroll
        for (int h = 0; h < H_; ++h) {
            float kh = kT[h][tt];
            const float* Wd = W1 + (192 + h) * J1 + j0;
            const float* Wb = W1 + (64 + h) * J1 + j0;
            const float* Wc = W1 + (128 + h) * J1 + j0;
            #pragma unroll
            for (int j = 0; j < 20; ++j)
                z1c[j] = fmaf(qk[h], Wd[j], fmaf(kh, Wb[j] - Wc[j], z1c[j]));
        }
        #pragma unroll
        for (int j = 0; j < 20; ++j) {
            float x = sigmoidf_(z1c[j]);
            const float* w2 = W2 + (j0 + j) * J2;
            #pragma unroll
            for (int m = 0; m < J2; ++m) z2[m] = fmaf(x, w2[m], z2[m]);
        }
    }

    float z3 = b3[0];
    #pragma unroll
    for (int m = 0; m < J2; ++m) z3 = fmaf(sigmoidf_(z2[m]), W3[m], z3);

    const int L = keys_length[b];
    float s = (tid < T_) ? ((tid < L) ? z3 : NEGV) * 0.125f : -3.0e38f;

    float mx = s;
    #pragma unroll
    for (int off = 32; off > 0; off >>= 1) mx = fmaxf(mx, __shfl_xor(mx, off));
    if ((tid & 63) == 0) red[tid >> 6] = mx;
    __syncthreads();
    mx = fmaxf(fmaxf(red[0], red[1]), fmaxf(red[2], red[3]));

    float e = (tid < T_) ? __expf(s - mx) : 0.0f;
    float sm = e;
    #pragma unroll
    for (int off = 32; off > 0; off >>= 1) sm += __shfl_xor(sm, off);
    __syncthreads();
    if ((tid & 63) == 0) red[4 + (tid >> 6)] = sm;
    __syncthreads();
    sm = red[4] + red[5] + red[6] + red[7];

    if (tid < T_) wsm[tid] = e / sm;
    __syncthreads();

    {
        int h = tid & 63, p = tid >> 6;
        float acc = 0.f;
        int t0 = p * 50;
        for (int t = t0; t < t0 + 50; ++t)
            acc = fmaf(wsm[t], kT[h][t], acc);
        part[tid] = acc;
    }
    __syncthreads();
    if (tid < 64) {
        out[bn * H_ + tid] = part[tid] + part[64 + tid] + part[128 + tid] + part[192 + tid];
    }
}

extern "C" void kernel_launch(void* const* d_in, const int* in_sizes, int n_in,
                              void* d_out, int out_size, void* d_ws, size_t ws_size,
                              hipStream_t stream) {
    const float* queries = (const float*)d_in[0];
    const float* keys    = (const float*)d_in[1];
    const int*   klen    = (const int*)  d_in[2];
    const float* W1 = (const float*)d_in[3];
    const float* b1 = (const float*)d_in[4];
    const float* W2 = (const float*)d_in[5];
    const float* b2 = (const float*)d_in[6];
    const float* W3 = (const float*)d_in[7];
    const float* b3 = (const float*)d_in[8];
    float* out = (float*)d_out;

    // ws layout (floats): wac[5120] wbc[5120] QW[2048*80] KW[25600*80]
    //                     then uints: W1F[2560] W2F[2304]
    const size_t nfloats = (size_t)(2 * H_ * J1 + B_ * N_ * J1 + B_ * T_ * J1);
    const size_t need = nfloats * 4 + (2560 + 2304) * 4;

    if (ws_size >= need) {
        float* wac = (float*)d_ws;
        float* wbc = wac + H_ * J1;
        float* QW  = wbc + H_ * J1;
        float* KW  = QW + B_ * N_ * J1;
        unsigned* W1F = (unsigned*)(KW + (size_t)B_ * T_ * J1);
        unsigned* W2F = W1F + 2560;

        prep_w  <<<dim3((H_ * J1 + 255) / 256),          dim3(256), 0, stream>>>(W1, wac, wbc);
        prep_qw <<<dim3((B_ * N_ * (J1/4) + 255) / 256), dim3(256), 0, stream>>>(queries, wac, b1, QW);
        prep_kw <<<dim3((B_ * T_ * (J1/4) + 255) / 256), dim3(256), 0, stream>>>(keys, wbc, KW);
        prep_w1f<<<dim3(10), dim3(256), 0, stream>>>(W1, W1F);
        prep_w2f<<<dim3(9),  dim3(256), 0, stream>>>(W2, W2F);
        attn_mfma<<<dim3(B_ * N_), dim3(256), 0, stream>>>(
            queries, keys, klen, b2, W3, b3, QW, KW,
            (const bf16x8*)W1F, (const bf16x8*)W2F, out);
    } else {
        attn_nows<<<dim3(B_ * N_), dim3(256), 0, stream>>>(
            queries, keys, klen, W1, b1, W2, b2, W3, b3, out);
    }
}

// Round 5
// 63.878 us; speedup vs baseline: 6.2414x; 1.9846x over previous
//
#include <hip/hip_runtime.h>
#include <hip/hip_bf16.h>
#include <math.h>

#define B_  128
#define N_  16
#define T_  200
#define H_  64
#define J1  80
#define J2  40
#define NTILE 13
#define NEGV -4294967295.0f   // -2^32 + 1

typedef __attribute__((ext_vector_type(8))) short bf16x8;
typedef __attribute__((ext_vector_type(4))) float f32x4;

__device__ __forceinline__ float sigmoidf_(float x) {
    return 1.0f / (1.0f + __expf(-x));
}
// branch-free RNE f32->bf16 (valid for finite inputs; no NaN/Inf here)
__device__ __forceinline__ short f2b(float x) {
    unsigned u = __float_as_uint(x);
    return (short)((u + 0x7FFF + ((u >> 16) & 1)) >> 16);
}
__device__ __forceinline__ unsigned pack2(float a, float b) {
    return (unsigned)(unsigned short)f2b(a) | ((unsigned)(unsigned short)f2b(b) << 16);
}

// --- prep 0: wac = W1a + W1c ; wbc = W1b - W1c ---------------------------
__global__ void prep_w(const float* __restrict__ W1,
                       float* __restrict__ wac, float* __restrict__ wbc) {
    int idx = blockIdx.x * 256 + threadIdx.x;          // idx = h*80 + j
    if (idx < H_ * J1) {
        wac[idx] = W1[idx]            + W1[128 * J1 + idx];
        wbc[idx] = W1[64 * J1 + idx]  - W1[128 * J1 + idx];
    }
}

// --- prep 1: QW[bn][j] = b1[j] + sum_h q[bn][h] * wac[h][j] --------------
__global__ void prep_qw(const float* __restrict__ q,
                        const float* __restrict__ wac,
                        const float* __restrict__ b1,
                        float* __restrict__ QW) {
    int idx = blockIdx.x * 256 + threadIdx.x;
    if (idx >= B_ * N_ * (J1 / 4)) return;
    int bn = idx / (J1 / 4);
    int j  = (idx % (J1 / 4)) * 4;
    float4 acc = *(const float4*)(b1 + j);
    const float* qp = q + bn * H_;
    for (int h = 0; h < H_; ++h) {
        float qh = qp[h];
        float4 w = *(const float4*)(wac + h * J1 + j);
        acc.x = fmaf(qh, w.x, acc.x);
        acc.y = fmaf(qh, w.y, acc.y);
        acc.z = fmaf(qh, w.z, acc.z);
        acc.w = fmaf(qh, w.w, acc.w);
    }
    *(float4*)(QW + bn * J1 + j) = acc;
}

// --- prep 2: keys -> frag-ordered bf16 A-fragments (per b, per 16-row tile)
// lane l of tile mt holds row t = mt*16+(l&15), k = 8*(l>>4)+r (af0) / +32 (af1)
__global__ void prep_kbf(const float* __restrict__ keys,
                         bf16x8* __restrict__ kbf0, bf16x8* __restrict__ kbf1) {
    int idx = blockIdx.x * 256 + threadIdx.x;          // (b*13+mt)*64 + l
    if (idx >= B_ * NTILE * 64) return;
    int l  = idx & 63, bm = idx >> 6;
    int mt = bm % NTILE, b = bm / NTILE;
    int t  = mt * 16 + (l & 15); if (t > T_ - 1) t = T_ - 1;   // clamp tail
    int rg = l >> 4;
    const float* kr = keys + ((size_t)(b * T_ + t)) * H_ + 8 * rg;
    float4 a0 = *(const float4*)(kr);
    float4 a1 = *(const float4*)(kr + 4);
    float4 a2 = *(const float4*)(kr + 32);
    float4 a3 = *(const float4*)(kr + 36);
    bf16x8 f0, f1;
    f0[0] = f2b(a0.x); f0[1] = f2b(a0.y); f0[2] = f2b(a0.z); f0[3] = f2b(a0.w);
    f0[4] = f2b(a1.x); f0[5] = f2b(a1.y); f0[6] = f2b(a1.z); f0[7] = f2b(a1.w);
    f1[0] = f2b(a2.x); f1[1] = f2b(a2.y); f1[2] = f2b(a2.z); f1[3] = f2b(a2.w);
    f1[4] = f2b(a3.x); f1[5] = f2b(a3.y); f1[6] = f2b(a3.z); f1[7] = f2b(a3.w);
    kbf0[idx] = f0; kbf1[idx] = f1;
}

// --- prep 3: W2 -> frag-ordered bf16 (k padded to 96, cols to 48) --------
// frag f = nt*3 + ks (nt<3, ks<3): k = ks*32+8*(l>>4)+r, m = nt*16+(l&15).
__global__ void prep_w2f(const float* __restrict__ W2, unsigned* __restrict__ W2F) {
    int idx = blockIdx.x * 256 + threadIdx.x;
    if (idx >= 9 * 64 * 4) return;
    int rp = idx & 3;
    int l  = (idx >> 2) & 63;
    int f  = idx >> 8;
    int m  = (f / 3) * 16 + (l & 15);
    int k0 = (f % 3) * 32 + 8 * (l >> 4) + 2 * rp;
    float a = (k0     < J1 && m < J2) ? W2[k0 * J2 + m]       : 0.0f;
    float b = (k0 + 1 < J1 && m < J2) ? W2[(k0 + 1) * J2 + m] : 0.0f;
    W2F[idx] = pack2(a, b);
}

// --- main (MFMA): block per (b,n); Z1 = K_bf16 @ (diag(q)W1d + wbc) + QW --
__global__ __launch_bounds__(256, 2) void attn_mfma(
        const float* __restrict__ queries, const float* __restrict__ keys,
        const int*   __restrict__ keys_length,
        const float* __restrict__ W1, const float* __restrict__ wbc,
        const float* __restrict__ b2, const float* __restrict__ W3,
        const float* __restrict__ b3,
        const float* __restrict__ QW,
        const bf16x8* __restrict__ kbf0, const bf16x8* __restrict__ kbf1,
        const bf16x8* __restrict__ W2F,
        float* __restrict__ out) {
    const int tid  = threadIdx.x;
    const int lane = tid & 63, wv = tid >> 6;
    const int bn   = (blockIdx.x & 7) * 256 + (blockIdx.x >> 3);  // XCD swizzle
    const int b    = bn >> 4;
    const int cl   = lane & 15, rg = lane >> 4;

    __shared__ short Bn[10 * 64 * 8];               // frag-ordered B_n (10 KB)
    __shared__ __align__(16) short X1[4][16][104];  // per-wave; stride 104
    __shared__ float z3s[NTILE * 16];
    __shared__ float wsm[T_];
    __shared__ float part[256];
    __shared__ float red[8];
    __shared__ float qls[H_];

    if (tid < H_) qls[tid] = queries[bn * H_ + tid];
    // zero own-wave X1 k-pad (cols 80..103); W2F pad rows are zero
    for (int i = lane; i < 16 * 24; i += 64)
        X1[wv][i / 24][80 + (i % 24)] = 0;
    __syncthreads();

    // build Bn[h][j] = q[h]*W1d[h][j] + wbc[h][j], stored frag-ordered:
    // f = (j/16)*2 + h/32 ; l = ((h%32)/8)*16 + j%16 ; r = h%8
    {
        int k  = tid >> 2, jb = (tid & 3) * 20;
        float qk_ = qls[k];
        int rgg = (k >> 3) & 3, r = k & 7, ks = k >> 5;
        const float* wd = W1  + (size_t)(192 + k) * J1 + jb;
        const float* wb = wbc + (size_t)k * J1 + jb;
        #pragma unroll
        for (int i = 0; i < 20; ++i) {
            int j = jb + i;
            int f = (j >> 4) * 2 + ks;
            int l2 = rgg * 16 + (j & 15);
            Bn[(f * 64 + l2) * 8 + r] = f2b(fmaf(qk_, wd[i], wb[i]));
        }
    }

    // per-lane constants (issued before the barrier; latency hides under it)
    float qwv[5];
    #pragma unroll
    for (int nt = 0; nt < 5; ++nt) qwv[nt] = QW[bn * J1 + cl + 16 * nt];
    bf16x8 w2f[9];
    #pragma unroll
    for (int f = 0; f < 9; ++f) w2f[f] = W2F[f * 64 + lane];
    float b2v[3], w3v[3];
    #pragma unroll
    for (int nt = 0; nt < 3; ++nt) {
        int m  = cl + 16 * nt;
        int mc = m < J2 ? m : J2 - 1;
        b2v[nt] = b2[mc];
        w3v[nt] = (m < J2) ? W3[mc] : 0.0f;
    }
    const float b3v = b3[0];
    __syncthreads();

    // B_n fragments resident in VGPRs
    bf16x8 bfr[10];
    #pragma unroll
    for (int f = 0; f < 10; ++f)
        bfr[f] = *(const bf16x8*)&Bn[(f * 64 + lane) * 8];

    const bf16x8* kb0 = kbf0 + (size_t)b * NTILE * 64;
    const bf16x8* kb1 = kbf1 + (size_t)b * NTILE * 64;
    const float*  kb  = keys + (size_t)b * T_ * H_;

    for (int mt = wv; mt < NTILE; mt += 4) {
        const int t0 = mt * 16;
        bf16x8 a0 = kb0[mt * 64 + lane];   // coalesced 16B, L2-hot
        bf16x8 a1 = kb1[mt * 64 + lane];

        // layer 1: acc init = QW (broadcast over rows)
        f32x4 acc[5];
        #pragma unroll
        for (int nt = 0; nt < 5; ++nt) {
            float qv = qwv[nt];
            acc[nt][0] = qv; acc[nt][1] = qv; acc[nt][2] = qv; acc[nt][3] = qv;
        }
        #pragma unroll
        for (int nt = 0; nt < 5; ++nt) {
            acc[nt] = __builtin_amdgcn_mfma_f32_16x16x32_bf16(a0, bfr[nt * 2 + 0], acc[nt], 0, 0, 0);
            acc[nt] = __builtin_amdgcn_mfma_f32_16x16x32_bf16(a1, bfr[nt * 2 + 1], acc[nt], 0, 0, 0);
        }

        // sigmoid -> X1 (C layout: row = rg*4+i, col = cl+16nt)
        #pragma unroll
        for (int nt = 0; nt < 5; ++nt) {
            #pragma unroll
            for (int i = 0; i < 4; ++i)
                X1[wv][rg * 4 + i][cl + 16 * nt] = f2b(sigmoidf_(acc[nt][i]));
        }

        // layer 2: acc2 init = b2 (broadcast over rows)
        f32x4 acc2[3];
        #pragma unroll
        for (int nt = 0; nt < 3; ++nt) {
            float bv = b2v[nt];
            acc2[nt][0] = bv; acc2[nt][1] = bv; acc2[nt][2] = bv; acc2[nt][3] = bv;
        }
        #pragma unroll
        for (int ks = 0; ks < 3; ++ks) {
            bf16x8 a2 = *(const bf16x8*)&X1[wv][cl][8 * rg + 32 * ks];
            acc2[0] = __builtin_amdgcn_mfma_f32_16x16x32_bf16(a2, w2f[0 + ks], acc2[0], 0, 0, 0);
            acc2[1] = __builtin_amdgcn_mfma_f32_16x16x32_bf16(a2, w2f[3 + ks], acc2[1], 0, 0, 0);
            acc2[2] = __builtin_amdgcn_mfma_f32_16x16x32_bf16(a2, w2f[6 + ks], acc2[2], 0, 0, 0);
        }

        // layer 3: z3[t] = sum_m sigmoid(z2[t][m]) * W3[m]
        float p0 = 0.f, p1 = 0.f, p2 = 0.f, p3 = 0.f;
        #pragma unroll
        for (int nt = 0; nt < 3; ++nt) {
            p0 = fmaf(sigmoidf_(acc2[nt][0]), w3v[nt], p0);
            p1 = fmaf(sigmoidf_(acc2[nt][1]), w3v[nt], p1);
            p2 = fmaf(sigmoidf_(acc2[nt][2]), w3v[nt], p2);
            p3 = fmaf(sigmoidf_(acc2[nt][3]), w3v[nt], p3);
        }
        #pragma unroll
        for (int off = 1; off < 16; off <<= 1) {
            p0 += __shfl_xor(p0, off);
            p1 += __shfl_xor(p1, off);
            p2 += __shfl_xor(p2, off);
            p3 += __shfl_xor(p3, off);
        }
        if (cl == 0) {
            z3s[t0 + rg * 4 + 0] = p0 + b3v;
            z3s[t0 + rg * 4 + 1] = p1 + b3v;
            z3s[t0 + rg * 4 + 2] = p2 + b3v;
            z3s[t0 + rg * 4 + 3] = p3 + b3v;
        }
    }
    __syncthreads();

    // mask + scale + softmax (thread tid owns t = tid)
    const int L = keys_length[b];
    float s = (tid < T_) ? ((tid < L) ? z3s[tid] : NEGV) * 0.125f : -3.0e38f;

    float mx = s;
    #pragma unroll
    for (int off = 32; off > 0; off >>= 1) mx = fmaxf(mx, __shfl_xor(mx, off));
    if ((tid & 63) == 0) red[tid >> 6] = mx;
    __syncthreads();
    mx = fmaxf(fmaxf(red[0], red[1]), fmaxf(red[2], red[3]));

    float e = (tid < T_) ? __expf(s - mx) : 0.0f;
    float sm = e;
    #pragma unroll
    for (int off = 32; off > 0; off >>= 1) sm += __shfl_xor(sm, off);
    __syncthreads();
    if ((tid & 63) == 0) red[4 + (tid >> 6)] = sm;
    __syncthreads();
    sm = red[4] + red[5] + red[6] + red[7];

    if (tid < T_) wsm[tid] = e / sm;
    __syncthreads();

    // out[h] = sum_t w[t] * keys[b][t][h]  (keys L2-hot, coalesced)
    {
        int h = tid & 63, p = tid >> 6;
        float acc = 0.f;
        int tb = p * 50;
        #pragma unroll 5
        for (int t = tb; t < tb + 50; ++t)
            acc = fmaf(wsm[t], kb[(size_t)t * H_ + h], acc);
        part[tid] = acc;
    }
    __syncthreads();
    if (tid < 64) {
        out[bn * H_ + tid] = part[tid] + part[64 + tid] + part[128 + tid] + part[192 + tid];
    }
}

// --- fallback (no workspace): round-3 verified pure-VALU kernel ----------
__global__ __launch_bounds__(256, 3) void attn_nows(
        const float* __restrict__ queries, const float* __restrict__ keys,
        const int*   __restrict__ keys_length,
        const float* __restrict__ W1, const float* __restrict__ b1,
        const float* __restrict__ W2, const float* __restrict__ b2,
        const float* __restrict__ W3, const float* __restrict__ b3,
        float* __restrict__ out) {
    const int tid = threadIdx.x;
    const int bn = (blockIdx.x & 7) * 256 + (blockIdx.x >> 3);
    const int b  = bn >> 4;

    __shared__ float kT[H_][T_ + 1];
    __shared__ float wsm[T_];
    __shared__ float part[256];
    __shared__ float red[8];
    __shared__ float QWq[J1];

    for (int idx = tid; idx < T_ * H_; idx += 256) {
        int t = idx >> 6, h = idx & 63;
        kT[h][t] = keys[(b * T_ + t) * H_ + h];
    }
    if (tid < J1) {
        float acc = b1[tid];
        const float* qp = queries + bn * H_;
        for (int h = 0; h < H_; ++h)
            acc = fmaf(qp[h], W1[h * J1 + tid] + W1[(128 + h) * J1 + tid], acc);
        QWq[tid] = acc;
    }
    __syncthreads();

    const int tt = (tid < T_) ? tid : 0;
    const float* qp = queries + bn * H_;

    float qk[H_];
    #pragma unroll
    for (int h = 0; h < H_; ++h) qk[h] = qp[h] * kT[h][tt];

    float z2[J2];
    #pragma unroll
    for (int m = 0; m < J2; ++m) z2[m] = b2[m];

    #pragma unroll 1
    for (int c = 0; c < 4; ++c) {
        const int j0 = c * 20;
        float z1c[20];
        #pragma unroll
        for (int j = 0; j < 20; ++j) z1c[j] = QWq[j0 + j];
        #pragma unroll
        for (int h = 0; h < H_; ++h) {
            float kh = kT[h][tt];
            const float* Wd = W1 + (192 + h) * J1 + j0;
            const float* Wb = W1 + (64 + h) * J1 + j0;
            const float* Wc = W1 + (128 + h) * J1 + j0;
            #pragma unroll
            for (int j = 0; j < 20; ++j)
                z1c[j] = fmaf(qk[h], Wd[j], fmaf(kh, Wb[j] - Wc[j], z1c[j]));
        }
        #pragma unroll
        for (int j = 0; j < 20; ++j) {
            float x = sigmoidf_(z1c[j]);
            const float* w2 = W2 + (j0 + j) * J2;
            #pragma unroll
            for (int m = 0; m < J2; ++m) z2[m] = fmaf(x, w2[m], z2[m]);
        }
    }

    float z3 = b3[0];
    #pragma unroll
    for (int m = 0; m < J2; ++m) z3 = fmaf(sigmoidf_(z2[m]), W3[m], z3);

    const int L = keys_length[b];
    float s = (tid < T_) ? ((tid < L) ? z3 : NEGV) * 0.125f : -3.0e38f;

    float mx = s;
    #pragma unroll
    for (int off = 32; off > 0; off >>= 1) mx = fmaxf(mx, __shfl_xor(mx, off));
    if ((tid & 63) == 0) red[tid >> 6] = mx;
    __syncthreads();
    mx = fmaxf(fmaxf(red[0], red[1]), fmaxf(red[2], red[3]));

    float e = (tid < T_) ? __expf(s - mx) : 0.0f;
    float sm = e;
    #pragma unroll
    for (int off = 32; off > 0; off >>= 1) sm += __shfl_xor(sm, off);
    __syncthreads();
    if ((tid & 63) == 0) red[4 + (tid >> 6)] = sm;
    __syncthreads();
    sm = red[4] + red[5] + red[6] + red[7];

    if (tid < T_) wsm[tid] = e / sm;
    __syncthreads();

    {
        int h = tid & 63, p = tid >> 6;
        float acc = 0.f;
        int t0 = p * 50;
        for (int t = t0; t < t0 + 50; ++t)
            acc = fmaf(wsm[t], kT[h][t], acc);
        part[tid] = acc;
    }
    __syncthreads();
    if (tid < 64) {
        out[bn * H_ + tid] = part[tid] + part[64 + tid] + part[128 + tid] + part[192 + tid];
    }
}

extern "C" void kernel_launch(void* const* d_in, const int* in_sizes, int n_in,
                              void* d_out, int out_size, void* d_ws, size_t ws_size,
                              hipStream_t stream) {
    const float* queries = (const float*)d_in[0];
    const float* keys    = (const float*)d_in[1];
    const int*   klen    = (const int*)  d_in[2];
    const float* W1 = (const float*)d_in[3];
    const float* b1 = (const float*)d_in[4];
    const float* W2 = (const float*)d_in[5];
    const float* b2 = (const float*)d_in[6];
    const float* W3 = (const float*)d_in[7];
    const float* b3 = (const float*)d_in[8];
    float* out = (float*)d_out;

    // ws layout: floats wac[5120] wbc[5120] QW[163840]; then
    // kbf0[128*13*64 frags x16B], kbf1[same], W2F[2304 uints]
    const size_t nf    = (size_t)(2 * H_ * J1 + B_ * N_ * J1);
    const size_t nkbf  = (size_t)B_ * NTILE * 64;         // frags per buffer
    const size_t need  = nf * 4 + 2 * nkbf * 16 + 2304 * 4;

    if (ws_size >= need) {
        float* wac = (float*)d_ws;
        float* wbc = wac + H_ * J1;
        float* QW  = wbc + H_ * J1;
        bf16x8* kbf0 = (bf16x8*)(QW + (size_t)B_ * N_ * J1);
        bf16x8* kbf1 = kbf0 + nkbf;
        unsigned* W2F = (unsigned*)(kbf1 + nkbf);

        prep_w  <<<dim3((H_ * J1 + 255) / 256),          dim3(256), 0, stream>>>(W1, wac, wbc);
        prep_qw <<<dim3((B_ * N_ * (J1/4) + 255) / 256), dim3(256), 0, stream>>>(queries, wac, b1, QW);
        prep_kbf<<<dim3((B_ * NTILE * 64 + 255) / 256),  dim3(256), 0, stream>>>(keys, kbf0, kbf1);
        prep_w2f<<<dim3(9), dim3(256), 0, stream>>>(W2, W2F);
        attn_mfma<<<dim3(B_ * N_), dim3(256), 0, stream>>>(
            queries, keys, klen, W1, wbc, b2, W3, b3, QW,
            kbf0, kbf1, (const bf16x8*)W2F, out);
    } else {
        attn_nows<<<dim3(B_ * N_), dim3(256), 0, stream>>>(
            queries, keys, klen, W1, b1, W2, b2, W3, b3, out);
    }
}